// Round 11
// baseline (95.569 us; speedup 1.0000x reference)
//
#include <hip/hip_runtime.h>

#define NN 8192
#define FD 128
#define BKF 256            // f32 K per step
#define NS (NN / BKF)      // 32 steps
#define RPB 16             // rows per block

typedef float f32x4 __attribute__((ext_vector_type(4)));
typedef short short8 __attribute__((ext_vector_type(8)));
typedef unsigned short ushort4v __attribute__((ext_vector_type(4)));
typedef unsigned short ushort8v __attribute__((ext_vector_type(8)));

__device__ __forceinline__ unsigned short f2bf(float f) {
  unsigned int u = __builtin_bit_cast(unsigned int, f);
  u += 0x7fffu + ((u >> 16) & 1u);   // round-to-nearest-even
  return (unsigned short)(u >> 16);
}
__device__ __forceinline__ float bf2f(unsigned short h) {
  unsigned int u = ((unsigned int)h) << 16;
  return __builtin_bit_cast(float, u);
}

// -------- Kernel 1: xk = x@kern (bf16), emitted as MFMA B-fragments + row-major
// bfrag[((kt*8 + cb)*64 + lane)*8 + j] = xk[kt*32 + (lane>>4)*8 + j][cb*16 + (lane&15)]
__global__ __launch_bounds__(256) void xk_kernel(
    const float* __restrict__ x, const float* __restrict__ kern,
    unsigned short* __restrict__ bfrag, unsigned short* __restrict__ xk_rm) {
  __shared__ __align__(16) unsigned short kl[FD * FD];
  __shared__ __align__(16) float xl[16 * FD];
  const int t = threadIdx.x;
  const int row0 = blockIdx.x * 16;

  #pragma unroll
  for (int j = 0; j < 16; ++j) {
    int idx = (j * 256 + t) * 4;
    f32x4 kv = *(const f32x4*)&kern[idx];
    ushort4v kw;
    #pragma unroll
    for (int q = 0; q < 4; ++q) kw[q] = f2bf(kv[q]);
    *(ushort4v*)&kl[idx] = kw;
  }
  #pragma unroll
  for (int j = 0; j < 2; ++j) {
    int idx = (j * 256 + t) * 4;
    *(f32x4*)&xl[idx] = *(const f32x4*)&x[(size_t)row0 * FD + idx];
  }
  __syncthreads();

  const int r0 = (t >> 5) * 2;
  const int c0 = (t & 31) * 4;
  float acc[2][4] = {};
  #pragma unroll 4
  for (int k = 0; k < FD; ++k) {
    ushort4v kq = *(const ushort4v*)&kl[k * FD + c0];
    float kv[4];
    #pragma unroll
    for (int q = 0; q < 4; ++q) kv[q] = bf2f(kq[q]);
    float x0 = xl[r0 * FD + k];
    float x1 = xl[(r0 + 1) * FD + k];
    #pragma unroll
    for (int q = 0; q < 4; ++q) {
      acc[0][q] += x0 * kv[q];
      acc[1][q] += x1 * kv[q];
    }
  }
  #pragma unroll
  for (int i = 0; i < 2; ++i) {
    const int r = row0 + r0 + i;
    const int kt = r >> 5;
    const int lhi = ((r >> 3) & 3) * 16;
    const int j = r & 7;
    ushort4v ow;
    #pragma unroll
    for (int q = 0; q < 4; ++q) {
      const int c = c0 + q;
      unsigned short bv = f2bf(acc[i][q]);
      ow[q] = bv;
      bfrag[(((size_t)kt * 8 + (c >> 4)) * 64 + (lhi + (c & 15))) * 8 + j] = bv;
    }
    *(ushort4v*)&xk_rm[(size_t)r * FD + c0] = ow;
  }
}

// -------- Kernel 2 (fused): full-K panel GEMM + rowsum + epilogue -----------
// Block = 16 rows x 128 cols x full K. 8 waves; wave w owns cols [w*16, w*16+16).
#define PREF(Lr, stp)                                                         \
  do {                                                                        \
    Lr[0] = *(const f32x4*)(ap + (size_t)(stp) * BKF);                        \
    Lr[1] = *(const f32x4*)(ap + (size_t)(stp) * BKF + 128);                  \
  } while (0)

#define STAGE(Lr, buf)                                                        \
  do {                                                                        \
    _Pragma("unroll") for (int i = 0; i < 2; ++i) {                           \
      ushort4v cw;                                                            \
      _Pragma("unroll") for (int q = 0; q < 4; ++q) cw[q] = f2bf(Lr[i][q]);   \
      rs += Lr[i][0] + Lr[i][1] + Lr[i][2] + Lr[i][3];                        \
      const int cc = scol + i * 128;                                          \
      *(ushort4v*)&sA[buf][srow * 256 + (cc ^ sxor)] = cw;                    \
    }                                                                         \
  } while (0)

#define LOAD_B(stp)                                                           \
  do {                                                                        \
    const int ktg = (stp) * 8;                                                \
    _Pragma("unroll") for (int h = 0; h < 8; ++h)                             \
      Bf[h] = *(const ushort8v*)(bp + (((size_t)(ktg + h) * 8 + w) << 9));    \
  } while (0)

#define MFMA_STEP(buf)                                                        \
  do {                                                                        \
    __builtin_amdgcn_s_setprio(1);                                            \
    _Pragma("unroll") for (int h = 0; h < 8; ++h) {                           \
      const int colu = (h * 32 + (l >> 4) * 8) ^ axor;                        \
      short8 aF = *(const short8*)&sA[buf][arow * 256 + colu];                \
      acc = __builtin_amdgcn_mfma_f32_16x16x32_bf16(aF, Bf[h], acc, 0, 0, 0); \
    }                                                                         \
    __builtin_amdgcn_s_setprio(0);                                            \
  } while (0)

#define LDS_BARRIER()                                                         \
  do {                                                                        \
    asm volatile("s_waitcnt lgkmcnt(0)" ::: "memory");                        \
    __builtin_amdgcn_sched_barrier(0);                                        \
    __builtin_amdgcn_s_barrier();                                             \
    __builtin_amdgcn_sched_barrier(0);                                        \
  } while (0)

__global__ __launch_bounds__(512, 4) void gcn_fused(
    const float* __restrict__ adj, const unsigned short* __restrict__ bfrag,
    const unsigned short* __restrict__ xk_rm, const float* __restrict__ beta,
    const float* __restrict__ bias, float* __restrict__ out) {
  __shared__ unsigned short sA[2][RPB * 256];   // bf16 tiles, 2 x 8 KB
  __shared__ float rs_lds[RPB];
  __shared__ float inv_lds[RPB];
  __shared__ float beta_lds[RPB];

  const int t = threadIdx.x;
  const int l = t & 63;
  const int w = t >> 6;                 // 0..7: output col-group
  const int row0 = blockIdx.x * RPB;

  // stage geometry: thread t -> srow = t>>5 (0..15), 2 chunks of 4 f32
  const int srow = t >> 5;
  const int scol = (t & 31) * 4;
  const int sxor = (srow & 7) << 3;
  const float* ap = adj + (size_t)(row0 + srow) * NN + scol;

  // consume geometry: lane l -> A row = l&15, k-chunk (l>>4)*8
  const int arow = l & 15;
  const int axor = (arow & 7) << 3;
  const unsigned short* bp = bfrag + (size_t)l * 8;

  f32x4 LrA[2], LrB[2];                 // depth-2 A register stages
  ushort8v Bf[8];
  f32x4 acc = {0.f, 0.f, 0.f, 0.f};
  float rs = 0.f;

  // prologue
  PREF(LrA, 0);
  STAGE(LrA, 0);                        // cold wait on step 0
  PREF(LrB, 1);                         // step 1 in flight
  LDS_BARRIER();

  for (int st = 0; st < NS; st += 2) {
    // even: consume buf0
    LOAD_B(st);                                  // L2 loads first
    if (st + 2 < NS) PREF(LrA, st + 2);          // HBM prefetch after
    __builtin_amdgcn_sched_barrier(0);
    MFMA_STEP(0);                                // waits B; A(st+1) complete
    STAGE(LrB, 1);                               // no wait (older than B)
    LDS_BARRIER();
    // odd: consume buf1
    LOAD_B(st + 1);
    if (st + 3 < NS) PREF(LrB, st + 3);
    __builtin_amdgcn_sched_barrier(0);
    MFMA_STEP(1);
    if (st + 2 < NS) STAGE(LrA, 0);
    LDS_BARRIER();
  }

  // ---- rowsum: 32 threads per srow hold disjoint col-chunks; width-32 reduce
  rs += __shfl_xor(rs, 1, 32);
  rs += __shfl_xor(rs, 2, 32);
  rs += __shfl_xor(rs, 4, 32);
  rs += __shfl_xor(rs, 8, 32);
  rs += __shfl_xor(rs, 16, 32);
  if ((l & 31) == 0) rs_lds[srow] = rs;
  __syncthreads();
  if (t < RPB) {
    const float bt = beta[row0 + t];
    beta_lds[t] = bt;
    inv_lds[t] = 1.0f / (rs_lds[t] + bt);
  }
  __syncthreads();

  // ---- epilogue: out = inv_deg*(agg + beta*xk) + bias (block-local) ----
  const int cg = w * 16 + (l & 15);            // C/D: col = l&15
  const float bias_v = bias[cg];
  #pragma unroll
  for (int j = 0; j < 4; ++j) {
    const int r = ((l >> 4) << 2) + j;         // C/D: row = (l>>4)*4 + j
    const float xkv = bf2f(xk_rm[(size_t)(row0 + r) * FD + cg]);
    out[(size_t)(row0 + r) * FD + cg] =
        (acc[j] + beta_lds[r] * xkv) * inv_lds[r] + bias_v;
  }
}

extern "C" void kernel_launch(void* const* d_in, const int* in_sizes, int n_in,
                              void* d_out, int out_size, void* d_ws, size_t ws_size,
                              hipStream_t stream) {
  const float* x    = (const float*)d_in[0];
  const float* adj  = (const float*)d_in[1];
  const float* kern = (const float*)d_in[2];
  const float* bias = (const float*)d_in[3];
  const float* beta = (const float*)d_in[4];
  float* out = (float*)d_out;

  char* ws = (char*)d_ws;
  unsigned short* bfrag = (unsigned short*)ws;                          // 2 MB
  unsigned short* xk_rm = (unsigned short*)(ws + (size_t)NN * FD * 2);  // 2 MB

  hipLaunchKernelGGL(xk_kernel, dim3(NN / 16), dim3(256), 0, stream,
                     x, kern, bfrag, xk_rm);
  hipLaunchKernelGGL(gcn_fused, dim3(NN / RPB), dim3(512), 0, stream,
                     adj, bfrag, xk_rm, beta, bias, out);
}

// Round 12
// 89.656 us; speedup vs baseline: 1.0659x; 1.0659x over previous
//
#include <hip/hip_runtime.h>

#define NN 8192
#define FD 128
#define RPB 32             // rows per block
#define SPL 8              // split-K slots
#define KW (NN / SPL)      // 1024 f32 per slice
#define NKS (KW / 32)      // 32 MFMA k-steps

typedef float f32x4 __attribute__((ext_vector_type(4)));
typedef short short8 __attribute__((ext_vector_type(8)));
typedef unsigned short ushort4v __attribute__((ext_vector_type(4)));
typedef unsigned short ushort8v __attribute__((ext_vector_type(8)));

__device__ __forceinline__ unsigned short f2bf(float f) {
  unsigned int u = __builtin_bit_cast(unsigned int, f);
  u += 0x7fffu + ((u >> 16) & 1u);   // round-to-nearest-even
  return (unsigned short)(u >> 16);
}
__device__ __forceinline__ float bf2f(unsigned short h) {
  unsigned int u = ((unsigned int)h) << 16;
  return __builtin_bit_cast(float, u);
}

// -------- Kernel 1: xk = x@kern (bf16), emitted as MFMA B-fragments + row-major
// bfrag[((kt*8 + cb)*64 + lane)*8 + j] = xk[kt*32 + (lane>>4)*8 + j][cb*16 + (lane&15)]
__global__ __launch_bounds__(256) void xk_kernel(
    const float* __restrict__ x, const float* __restrict__ kern,
    unsigned short* __restrict__ bfrag, unsigned short* __restrict__ xk_rm) {
  __shared__ __align__(16) unsigned short kl[FD * FD];
  __shared__ __align__(16) float xl[16 * FD];
  const int t = threadIdx.x;
  const int row0 = blockIdx.x * 16;

  #pragma unroll
  for (int j = 0; j < 16; ++j) {
    int idx = (j * 256 + t) * 4;
    f32x4 kv = *(const f32x4*)&kern[idx];
    ushort4v kw;
    #pragma unroll
    for (int q = 0; q < 4; ++q) kw[q] = f2bf(kv[q]);
    *(ushort4v*)&kl[idx] = kw;
  }
  #pragma unroll
  for (int j = 0; j < 2; ++j) {
    int idx = (j * 256 + t) * 4;
    *(f32x4*)&xl[idx] = *(const f32x4*)&x[(size_t)row0 * FD + idx];
  }
  __syncthreads();

  const int r0 = (t >> 5) * 2;
  const int c0 = (t & 31) * 4;
  float acc[2][4] = {};
  #pragma unroll 4
  for (int k = 0; k < FD; ++k) {
    ushort4v kq = *(const ushort4v*)&kl[k * FD + c0];
    float kv[4];
    #pragma unroll
    for (int q = 0; q < 4; ++q) kv[q] = bf2f(kq[q]);
    float x0 = xl[r0 * FD + k];
    float x1 = xl[(r0 + 1) * FD + k];
    #pragma unroll
    for (int q = 0; q < 4; ++q) {
      acc[0][q] += x0 * kv[q];
      acc[1][q] += x1 * kv[q];
    }
  }
  #pragma unroll
  for (int i = 0; i < 2; ++i) {
    const int r = row0 + r0 + i;
    const int kt = r >> 5;
    const int lhi = ((r >> 3) & 3) * 16;
    const int j = r & 7;
    ushort4v ow;
    #pragma unroll
    for (int q = 0; q < 4; ++q) {
      const int c = c0 + q;
      unsigned short bv = f2bf(acc[i][q]);
      ow[q] = bv;
      bfrag[(((size_t)kt * 8 + (c >> 4)) * 64 + (lhi + (c & 15))) * 8 + j] = bv;
    }
    *(ushort4v*)&xk_rm[(size_t)r * FD + c0] = ow;
  }
}

// -------- Kernel 2: phase-separated split-K MFMA ----------------------------
// Stage WHOLE 32x1024 A-panel once (sequential 4KB runs/row), barrier,
// then barrier-free compute (B-loads + LDS reads + MFMA only).
__global__ __launch_bounds__(256, 2) void gcn_mm(
    const float* __restrict__ adj, const unsigned short* __restrict__ bfrag,
    unsigned short* __restrict__ parts, float* __restrict__ rowpart) {
  __shared__ unsigned short panel[RPB * 1024];   // 64 KB bf16
  __shared__ float rs_l[4][8];

  const int t = threadIdx.x;
  const int l = t & 63;
  const int w = t >> 6;
  const int b = blockIdx.x;
  const int s = b & (SPL - 1);                 // K-slot == XCD (round-robin)
  const int row0 = (b >> 3) * RPB;
  const int kbase = s * KW;
  const int kt0 = s * NKS;

  // ======== PHASE 1: stage panel (f32 -> bf16, + rowsum) ========
  // wave w owns local rows w*8..w*8+7; inst i: row rr=i>>2, chunk ch=i&3 (1KB)
  const float* ap = adj + (size_t)row0 * NN + kbase;
  float rsum[8] = {};

  #pragma unroll
  for (int half = 0; half < 2; ++half) {
    f32x4 v[16];
    #pragma unroll
    for (int i16 = 0; i16 < 16; ++i16) {
      const int i = half * 16 + i16;
      const int rr = i >> 2, ch = i & 3;
      v[i16] = *(const f32x4*)(ap + (size_t)(w * 8 + rr) * NN + ch * 256 + l * 4);
    }
    #pragma unroll
    for (int i16 = 0; i16 < 16; ++i16) {
      const int i = half * 16 + i16;
      const int rr = i >> 2, ch = i & 3;
      const int row_l = w * 8 + rr;
      ushort4v cw;
      #pragma unroll
      for (int q = 0; q < 4; ++q) cw[q] = f2bf(v[i16][q]);
      rsum[rr] += v[i16][0] + v[i16][1] + v[i16][2] + v[i16][3];
      const int unit = (ch * 32 + (l >> 1)) ^ (row_l & 7);
      *(ushort4v*)&panel[row_l * 1024 + unit * 8 + (l & 1) * 4] = cw;
    }
  }

  // wave-reduce rowsums (all 64 lanes hold disjoint chunks of each row)
  #pragma unroll
  for (int rr = 0; rr < 8; ++rr) {
    rsum[rr] += __shfl_xor(rsum[rr], 1);
    rsum[rr] += __shfl_xor(rsum[rr], 2);
    rsum[rr] += __shfl_xor(rsum[rr], 4);
    rsum[rr] += __shfl_xor(rsum[rr], 8);
    rsum[rr] += __shfl_xor(rsum[rr], 16);
    rsum[rr] += __shfl_xor(rsum[rr], 32);
  }
  if (l == 0) {
    #pragma unroll
    for (int rr = 0; rr < 8; ++rr) rs_l[w][rr] = rsum[rr];
  }
  __syncthreads();

  // ======== PHASE 2: barrier-free compute ========
  // wave w owns cols w*32..w*32+31 (cb = 2w, 2w+1)
  const unsigned short* bp = bfrag + (size_t)l * 8;
  f32x4 acc[2][2] = {};

  #pragma unroll 4
  for (int ks = 0; ks < NKS; ++ks) {
    ushort8v Bf0 = *(const ushort8v*)(bp + (((size_t)(kt0 + ks) * 8 + 2 * w) << 9));
    ushort8v Bf1 = *(const ushort8v*)(bp + (((size_t)(kt0 + ks) * 8 + 2 * w + 1) << 9));
    #pragma unroll
    for (int mf = 0; mf < 2; ++mf) {
      const int row = (l & 15) + 16 * mf;
      const int unit = (ks * 4 + (l >> 4)) ^ (row & 7);
      short8 aF = *(const short8*)&panel[row * 1024 + unit * 8];
      acc[mf][0] = __builtin_amdgcn_mfma_f32_16x16x32_bf16(aF, Bf0, acc[mf][0], 0, 0, 0);
      acc[mf][1] = __builtin_amdgcn_mfma_f32_16x16x32_bf16(aF, Bf1, acc[mf][1], 0, 0, 0);
    }
  }

  // ---- rowpart: 32 rows, value from rs_l (written pre-sync) ----
  if (t < RPB)
    rowpart[(size_t)s * NN + row0 + t] = rs_l[t >> 3][t & 7];

  // ---- store bf16 partial tile: C/D col = l&15, row = (l>>4)*4 + j ----
  unsigned short* pp = parts + ((size_t)s * NN + row0) * FD + w * 32;
  #pragma unroll
  for (int mf = 0; mf < 2; ++mf)
    #pragma unroll
    for (int ci = 0; ci < 2; ++ci)
      #pragma unroll
      for (int jj = 0; jj < 4; ++jj) {
        const int r = mf * 16 + ((l >> 4) << 2) + jj;
        pp[(size_t)r * FD + ci * 16 + (l & 15)] = f2bf(acc[mf][ci][jj]);
      }
}

// -------- Kernel 3: reduce S partials + epilogue ---------------------------
__global__ __launch_bounds__(256) void gcn_fin(
    const unsigned short* __restrict__ parts, const float* __restrict__ rowpart,
    const unsigned short* __restrict__ xk_rm, const float* __restrict__ beta,
    const float* __restrict__ bias, float* __restrict__ out) {
  const int t = threadIdx.x;
  const int r = blockIdx.x * 16 + (t >> 4);
  const int c0 = (t & 15) * 8;

  float rsum = 0.f;
  for (int s = 0; s < SPL; ++s) rsum += rowpart[(size_t)s * NN + r];
  const float bt = beta[r];
  const float inv = 1.0f / (rsum + bt);

  float a[8] = {0.f, 0.f, 0.f, 0.f, 0.f, 0.f, 0.f, 0.f};
  for (int s = 0; s < SPL; ++s) {
    ushort8v pv = *(const ushort8v*)&parts[((size_t)s * NN + r) * FD + c0];
    #pragma unroll
    for (int q = 0; q < 8; ++q) a[q] += bf2f(pv[q]);
  }
  ushort8v xv = *(const ushort8v*)&xk_rm[(size_t)r * FD + c0];
  f32x4 o0, o1;
  #pragma unroll
  for (int q = 0; q < 4; ++q) {
    o0[q] = (a[q] + bt * bf2f(xv[q])) * inv + bias[c0 + q];
    o1[q] = (a[4 + q] + bt * bf2f(xv[4 + q])) * inv + bias[c0 + 4 + q];
  }
  *(f32x4*)&out[(size_t)r * FD + c0] = o0;
  *(f32x4*)&out[(size_t)r * FD + c0 + 4] = o1;
}

extern "C" void kernel_launch(void* const* d_in, const int* in_sizes, int n_in,
                              void* d_out, int out_size, void* d_ws, size_t ws_size,
                              hipStream_t stream) {
  const float* x    = (const float*)d_in[0];
  const float* adj  = (const float*)d_in[1];
  const float* kern = (const float*)d_in[2];
  const float* bias = (const float*)d_in[3];
  const float* beta = (const float*)d_in[4];
  float* out = (float*)d_out;

  char* ws = (char*)d_ws;
  unsigned short* bfrag = (unsigned short*)ws;                          // 2 MB
  unsigned short* xk_rm = (unsigned short*)(ws + (size_t)NN * FD * 2);  // 2 MB
  const size_t off_rowpart = (size_t)NN * FD * 4;
  float* rowpart = (float*)(ws + off_rowpart);                          // 256 KB
  const size_t off_parts = off_rowpart + (size_t)SPL * NN * 4;
  unsigned short* parts = (unsigned short*)(ws + off_parts);            // 16 MB

  hipLaunchKernelGGL(xk_kernel, dim3(NN / 16), dim3(256), 0, stream,
                     x, kern, bfrag, xk_rm);
  hipLaunchKernelGGL(gcn_mm, dim3((NN / RPB) * SPL), dim3(256), 0, stream,
                     adj, bfrag, parts, rowpart);
  hipLaunchKernelGGL(gcn_fin, dim3(NN / 16), dim3(256), 0, stream,
                     parts, rowpart, xk_rm, beta, bias, out);
}

// Round 13
// 86.882 us; speedup vs baseline: 1.1000x; 1.0319x over previous
//
#include <hip/hip_runtime.h>

#define NN 8192
#define FD 128
#define BK 128    // K per step (f32 elems)

typedef float f32x4 __attribute__((ext_vector_type(4)));
typedef short short8 __attribute__((ext_vector_type(8)));
typedef unsigned short ushort4v __attribute__((ext_vector_type(4)));
typedef unsigned short ushort8v __attribute__((ext_vector_type(8)));

__device__ __forceinline__ unsigned short f2bf(float f) {
  unsigned int u = __builtin_bit_cast(unsigned int, f);
  u += 0x7fffu + ((u >> 16) & 1u);   // round-to-nearest-even
  return (unsigned short)(u >> 16);
}
__device__ __forceinline__ float bf2f(unsigned short h) {
  unsigned int u = ((unsigned int)h) << 16;
  return __builtin_bit_cast(float, u);
}

// -------- Kernel 1: xk = x@kern (bf16), emitted as MFMA B-fragments + row-major
// bfrag[((kt*8 + cb)*64 + lane)*8 + j] = xk[kt*32 + (lane>>4)*8 + j][cb*16 + (lane&15)]
__global__ __launch_bounds__(256) void xk_kernel(
    const float* __restrict__ x, const float* __restrict__ kern,
    unsigned short* __restrict__ bfrag, unsigned short* __restrict__ xk_rm) {
  __shared__ __align__(16) unsigned short kl[FD * FD];
  __shared__ __align__(16) float xl[16 * FD];
  const int t = threadIdx.x;
  const int row0 = blockIdx.x * 16;

  #pragma unroll
  for (int j = 0; j < 16; ++j) {
    int idx = (j * 256 + t) * 4;
    f32x4 kv = *(const f32x4*)&kern[idx];
    ushort4v kw;
    #pragma unroll
    for (int q = 0; q < 4; ++q) kw[q] = f2bf(kv[q]);
    *(ushort4v*)&kl[idx] = kw;
  }
  #pragma unroll
  for (int j = 0; j < 2; ++j) {
    int idx = (j * 256 + t) * 4;
    *(f32x4*)&xl[idx] = *(const f32x4*)&x[(size_t)row0 * FD + idx];
  }
  __syncthreads();

  const int r0 = (t >> 5) * 2;
  const int c0 = (t & 31) * 4;
  float acc[2][4] = {};
  #pragma unroll 4
  for (int k = 0; k < FD; ++k) {
    ushort4v kq = *(const ushort4v*)&kl[k * FD + c0];
    float kv[4];
    #pragma unroll
    for (int q = 0; q < 4; ++q) kv[q] = bf2f(kq[q]);
    float x0 = xl[r0 * FD + k];
    float x1 = xl[(r0 + 1) * FD + k];
    #pragma unroll
    for (int q = 0; q < 4; ++q) {
      acc[0][q] += x0 * kv[q];
      acc[1][q] += x1 * kv[q];
    }
  }
  #pragma unroll
  for (int i = 0; i < 2; ++i) {
    const int r = row0 + r0 + i;
    const int kt = r >> 5;
    const int lhi = ((r >> 3) & 3) * 16;
    const int j = r & 7;
    ushort4v ow;
    #pragma unroll
    for (int q = 0; q < 4; ++q) {
      const int c = c0 + q;
      unsigned short bv = f2bf(acc[i][q]);
      ow[q] = bv;
      bfrag[(((size_t)kt * 8 + (c >> 4)) * 64 + (lhi + (c & 15))) * 8 + j] = bv;
    }
    *(ushort4v*)&xk_rm[(size_t)r * FD + c0] = ow;
  }
}

// -------- Kernel 2: split-K MFMA, 16 waves/CU, NT adj stream ----------------
// Block = 32 rows x 128 cols x (NN/S) K-slice; wave w owns cols [w*32,w*32+32).
#define PREF(Lr, stp)                                                         \
  do {                                                                        \
    _Pragma("unroll") for (int i = 0; i < 4; ++i)                             \
        Lr[i] = __builtin_nontemporal_load(                                   \
            (const f32x4*)(ap + (size_t)(i * 8) * NN + (stp) * BK));          \
  } while (0)

#define STAGE(Lr, buf)                                                        \
  do {                                                                        \
    _Pragma("unroll") for (int i = 0; i < 4; ++i) {                           \
      ushort4v cw;                                                            \
      _Pragma("unroll") for (int q = 0; q < 4; ++q) cw[q] = f2bf(Lr[i][q]);   \
      rs[i] += Lr[i][0] + Lr[i][1] + Lr[i][2] + Lr[i][3];                     \
      const int row_l = i * 8 + srow;                                         \
      *(ushort4v*)&sA[buf][row_l * 128 +                                      \
                           (scol ^ ((row_l & 7) << 3))] = cw;                 \
    }                                                                         \
  } while (0)

#define LOAD_B(stp)                                                           \
  do {                                                                        \
    const int ktg = kt0 + (stp) * 4;                                          \
    _Pragma("unroll") for (int kk = 0; kk < 4; ++kk)                          \
        _Pragma("unroll") for (int ci = 0; ci < 2; ++ci)                      \
            Bf[kk * 2 + ci] = *(const ushort8v*)(bp +                         \
                (((size_t)(ktg + kk) * 8 + (w * 2 + ci)) << 9));              \
  } while (0)

#define MFMA_STEP(buf)                                                        \
  do {                                                                        \
    __builtin_amdgcn_s_setprio(1);                                            \
    _Pragma("unroll") for (int kk = 0; kk < 4; ++kk) {                        \
      short8 aF[2];                                                           \
      _Pragma("unroll") for (int mf = 0; mf < 2; ++mf) {                      \
        const int r = mf * 16 + (l & 15);                                     \
        const int colu = kk * 32 + (l >> 4) * 8;                              \
        aF[mf] = *(const short8*)&sA[buf][r * 128 +                           \
                                          (colu ^ ((r & 7) << 3))];           \
      }                                                                       \
      _Pragma("unroll") for (int mf = 0; mf < 2; ++mf)                        \
          _Pragma("unroll") for (int ci = 0; ci < 2; ++ci)                    \
              acc[mf][ci] = __builtin_amdgcn_mfma_f32_16x16x32_bf16(          \
                  aF[mf], Bf[kk * 2 + ci], acc[mf][ci], 0, 0, 0);             \
    }                                                                         \
    __builtin_amdgcn_s_setprio(0);                                            \
  } while (0)

#define LDS_BARRIER()                                                         \
  do {                                                                        \
    asm volatile("s_waitcnt lgkmcnt(0)" ::: "memory");                        \
    __builtin_amdgcn_sched_barrier(0);                                        \
    __builtin_amdgcn_s_barrier();                                             \
  } while (0)

template <int S>
__global__ __launch_bounds__(256, 4) void gcn_mm(
    const float* __restrict__ adj, const unsigned short* __restrict__ bfrag,
    unsigned short* __restrict__ parts, float* __restrict__ rowpart) {
  constexpr int KW = NN / S;       // K per slot
  constexpr int NS = KW / BK;      // steps (8 at S=8), always even
  __shared__ unsigned short sA[2][32 * 128];   // 16 KB

  const int t = threadIdx.x;
  const int l = t & 63;
  const int w = t >> 6;
  const int b = blockIdx.x;
  const int s = b & (S - 1);                  // K-slot == XCD (round-robin)
  const int row0 = (b / S) * 32;              // block's 32 rows
  const int kbase = s * KW;
  const int kt0 = s * (KW / 32);

  // A stage geometry: instr i, thread t -> row = i*8 + (t>>5), 512B/row chunks
  const int srow = t >> 5;                    // 0..7
  const int scol = (t & 31) * 4;              // f32 (and bf16) col within step
  const float* ap = adj + (size_t)(row0 + srow) * NN + kbase + scol;
  const unsigned short* bp = bfrag + (size_t)l * 8;

  f32x4 LrA[4], LrB[4];            // depth-2 A register stages
  ushort8v Bf[8];
  f32x4 acc[2][2] = {};
  float rs[4] = {};

  // prologue
  PREF(LrA, 0);
  STAGE(LrA, 0);                   // cold wait on step 0
  PREF(LrB, 1);                    // step 1 in flight across step 0's MFMA
  LDS_BARRIER();

  for (int st = 0; st < NS; st += 2) {
    // even: consume buf0
    LOAD_B(st);                                // B younger than A(st+1) queue-wise
    if (st + 2 < NS) PREF(LrA, st + 2);
    __builtin_amdgcn_sched_barrier(0);
    MFMA_STEP(0);                              // waits B only; A(st+2) survives
    STAGE(LrB, 1);                             // A(st+1): issued a full step ago
    LDS_BARRIER();
    // odd: consume buf1
    LOAD_B(st + 1);
    if (st + 3 < NS) PREF(LrB, st + 3);
    __builtin_amdgcn_sched_barrier(0);
    MFMA_STEP(1);
    if (st + 2 < NS) STAGE(LrA, 0);
    LDS_BARRIER();
  }

  // ---- rowsum: reduce over the 32 k-lanes sharing each row ----
  #pragma unroll
  for (int i = 0; i < 4; ++i) {
    rs[i] += __shfl_xor(rs[i], 1);
    rs[i] += __shfl_xor(rs[i], 2);
    rs[i] += __shfl_xor(rs[i], 4);
    rs[i] += __shfl_xor(rs[i], 8);
    rs[i] += __shfl_xor(rs[i], 16);
  }
  if ((l & 31) == 0) {
    #pragma unroll
    for (int i = 0; i < 4; ++i)
      rowpart[(size_t)s * NN + row0 + i * 8 + srow] = rs[i];
  }

  // ---- store bf16 partial tile (NT): C/D col = l&15, row = (l>>4)*4 + j ----
  unsigned short* pp = parts + ((size_t)s * NN + row0) * FD + w * 32;
  #pragma unroll
  for (int mf = 0; mf < 2; ++mf)
    #pragma unroll
    for (int ci = 0; ci < 2; ++ci)
      #pragma unroll
      for (int j = 0; j < 4; ++j) {
        const int r = mf * 16 + ((l >> 4) << 2) + j;
        __builtin_nontemporal_store(
            f2bf(acc[mf][ci][j]), &pp[(size_t)r * FD + ci * 16 + (l & 15)]);
      }
}

// -------- Kernel 3: reduce S partials + epilogue (NT streaming) -------------
__global__ __launch_bounds__(256) void gcn_fin(
    const unsigned short* __restrict__ parts, const float* __restrict__ rowpart,
    const unsigned short* __restrict__ xk_rm, const float* __restrict__ beta,
    const float* __restrict__ bias, float* __restrict__ out, int S) {
  const int t = threadIdx.x;
  const int r = blockIdx.x * 16 + (t >> 4);
  const int c0 = (t & 15) * 8;

  float rsum = 0.f;
  for (int s = 0; s < S; ++s) rsum += rowpart[(size_t)s * NN + r];
  const float bt = beta[r];
  const float inv = 1.0f / (rsum + bt);

  float a[8] = {0.f, 0.f, 0.f, 0.f, 0.f, 0.f, 0.f, 0.f};
  for (int s = 0; s < S; ++s) {
    ushort8v pv = __builtin_nontemporal_load(
        (const ushort8v*)&parts[((size_t)s * NN + r) * FD + c0]);
    #pragma unroll
    for (int q = 0; q < 8; ++q) a[q] += bf2f(pv[q]);
  }
  ushort8v xv = *(const ushort8v*)&xk_rm[(size_t)r * FD + c0];
  f32x4 o0, o1;
  #pragma unroll
  for (int q = 0; q < 4; ++q) {
    o0[q] = (a[q] + bt * bf2f(xv[q])) * inv + bias[c0 + q];
    o1[q] = (a[4 + q] + bt * bf2f(xv[4 + q])) * inv + bias[c0 + 4 + q];
  }
  __builtin_nontemporal_store(o0, (f32x4*)&out[(size_t)r * FD + c0]);
  __builtin_nontemporal_store(o1, (f32x4*)&out[(size_t)r * FD + c0 + 4]);
}

extern "C" void kernel_launch(void* const* d_in, const int* in_sizes, int n_in,
                              void* d_out, int out_size, void* d_ws, size_t ws_size,
                              hipStream_t stream) {
  const float* x    = (const float*)d_in[0];
  const float* adj  = (const float*)d_in[1];
  const float* kern = (const float*)d_in[2];
  const float* bias = (const float*)d_in[3];
  const float* beta = (const float*)d_in[4];
  float* out = (float*)d_out;

  char* ws = (char*)d_ws;
  unsigned short* bfrag = (unsigned short*)ws;                          // 2 MB
  unsigned short* xk_rm = (unsigned short*)(ws + (size_t)NN * FD * 2);  // 2 MB
  const size_t off_rowpart = (size_t)NN * FD * 4;
  float* rowpart = (float*)(ws + off_rowpart);                          // 256 KB
  const size_t off_parts = off_rowpart + (size_t)8 * NN * 4;
  unsigned short* parts = (unsigned short*)(ws + off_parts);            // 16 MB @ S=8

  int S = 8;
  while (S > 1 && off_parts + (size_t)S * NN * FD * 2 > ws_size) S >>= 1;

  hipLaunchKernelGGL(xk_kernel, dim3(NN / 16), dim3(256), 0, stream,
                     x, kern, bfrag, xk_rm);

  dim3 blk(256);
  switch (S) {
    case 8: hipLaunchKernelGGL(gcn_mm<8>, dim3(256 * 8), blk, 0, stream, adj, bfrag, parts, rowpart); break;
    case 4: hipLaunchKernelGGL(gcn_mm<4>, dim3(256 * 4), blk, 0, stream, adj, bfrag, parts, rowpart); break;
    case 2: hipLaunchKernelGGL(gcn_mm<2>, dim3(256 * 2), blk, 0, stream, adj, bfrag, parts, rowpart); break;
    default: hipLaunchKernelGGL(gcn_mm<1>, dim3(256), blk, 0, stream, adj, bfrag, parts, rowpart); break;
  }

  hipLaunchKernelGGL(gcn_fin, dim3(NN / 16), dim3(256), 0, stream,
                     parts, rowpart, xk_rm, beta, bias, out, S);
}

// Round 14
// 80.732 us; speedup vs baseline: 1.1838x; 1.0762x over previous
//
#include <hip/hip_runtime.h>

#define NN 8192
#define FD 128
#define BK 128    // K per step (f32 elems)

typedef float f32x4 __attribute__((ext_vector_type(4)));
typedef short short8 __attribute__((ext_vector_type(8)));
typedef unsigned short ushort4v __attribute__((ext_vector_type(4)));
typedef unsigned short ushort8v __attribute__((ext_vector_type(8)));

__device__ __forceinline__ unsigned short f2bf(float f) {
  unsigned int u = __builtin_bit_cast(unsigned int, f);
  u += 0x7fffu + ((u >> 16) & 1u);   // round-to-nearest-even
  return (unsigned short)(u >> 16);
}
__device__ __forceinline__ float bf2f(unsigned short h) {
  unsigned int u = ((unsigned int)h) << 16;
  return __builtin_bit_cast(float, u);
}

// -------- Kernel 1: xk = x@kern (bf16), emitted as MFMA B-fragments + row-major
// bfrag[((kt*8 + cb)*64 + lane)*8 + j] = xk[kt*32 + (lane>>4)*8 + j][cb*16 + (lane&15)]
__global__ __launch_bounds__(256) void xk_kernel(
    const float* __restrict__ x, const float* __restrict__ kern,
    unsigned short* __restrict__ bfrag, unsigned short* __restrict__ xk_rm) {
  __shared__ __align__(16) unsigned short kl[FD * FD];
  __shared__ __align__(16) float xl[16 * FD];
  const int t = threadIdx.x;
  const int row0 = blockIdx.x * 16;

  #pragma unroll
  for (int j = 0; j < 16; ++j) {
    int idx = (j * 256 + t) * 4;
    f32x4 kv = *(const f32x4*)&kern[idx];
    ushort4v kw;
    #pragma unroll
    for (int q = 0; q < 4; ++q) kw[q] = f2bf(kv[q]);
    *(ushort4v*)&kl[idx] = kw;
  }
  #pragma unroll
  for (int j = 0; j < 2; ++j) {
    int idx = (j * 256 + t) * 4;
    *(f32x4*)&xl[idx] = *(const f32x4*)&x[(size_t)row0 * FD + idx];
  }
  __syncthreads();

  const int r0 = (t >> 5) * 2;
  const int c0 = (t & 31) * 4;
  float acc[2][4] = {};
  #pragma unroll 4
  for (int k = 0; k < FD; ++k) {
    ushort4v kq = *(const ushort4v*)&kl[k * FD + c0];
    float kv[4];
    #pragma unroll
    for (int q = 0; q < 4; ++q) kv[q] = bf2f(kq[q]);
    float x0 = xl[r0 * FD + k];
    float x1 = xl[(r0 + 1) * FD + k];
    #pragma unroll
    for (int q = 0; q < 4; ++q) {
      acc[0][q] += x0 * kv[q];
      acc[1][q] += x1 * kv[q];
    }
  }
  #pragma unroll
  for (int i = 0; i < 2; ++i) {
    const int r = row0 + r0 + i;
    const int kt = r >> 5;
    const int lhi = ((r >> 3) & 3) * 16;
    const int j = r & 7;
    ushort4v ow;
    #pragma unroll
    for (int q = 0; q < 4; ++q) {
      const int c = c0 + q;
      unsigned short bv = f2bf(acc[i][q]);
      ow[q] = bv;
      bfrag[(((size_t)kt * 8 + (c >> 4)) * 64 + (lhi + (c & 15))) * 8 + j] = bv;
    }
    *(ushort4v*)&xk_rm[(size_t)r * FD + c0] = ow;
  }
}

// -------- Kernel 2: split-K MFMA, 16 waves/CU, block-cooperative A stage ----
// Block = 32 rows x 128 cols x (NN/S) K-slice; wave w owns cols [w*32,w*32+32).
#define PREF(Lr, stp)                                                         \
  do {                                                                        \
    _Pragma("unroll") for (int i = 0; i < 4; ++i)                             \
        Lr[i] = *(const f32x4*)(ap + (size_t)(i * 8) * NN + (stp) * BK);      \
  } while (0)

#define STAGE(Lr, buf)                                                        \
  do {                                                                        \
    _Pragma("unroll") for (int i = 0; i < 4; ++i) {                           \
      ushort4v cw;                                                            \
      _Pragma("unroll") for (int q = 0; q < 4; ++q) cw[q] = f2bf(Lr[i][q]);   \
      rs[i] += Lr[i][0] + Lr[i][1] + Lr[i][2] + Lr[i][3];                     \
      const int row_l = i * 8 + srow;                                         \
      *(ushort4v*)&sA[buf][row_l * 128 +                                      \
                           (scol ^ ((row_l & 7) << 3))] = cw;                 \
    }                                                                         \
  } while (0)

#define LOAD_B(stp)                                                           \
  do {                                                                        \
    const int ktg = kt0 + (stp) * 4;                                          \
    _Pragma("unroll") for (int kk = 0; kk < 4; ++kk)                          \
        _Pragma("unroll") for (int ci = 0; ci < 2; ++ci)                      \
            Bf[kk * 2 + ci] = *(const ushort8v*)(bp +                         \
                (((size_t)(ktg + kk) * 8 + (w * 2 + ci)) << 9));              \
  } while (0)

#define MFMA_STEP(buf)                                                        \
  do {                                                                        \
    __builtin_amdgcn_s_setprio(1);                                            \
    _Pragma("unroll") for (int kk = 0; kk < 4; ++kk) {                        \
      short8 aF[2];                                                           \
      _Pragma("unroll") for (int mf = 0; mf < 2; ++mf) {                      \
        const int r = mf * 16 + (l & 15);                                     \
        const int colu = kk * 32 + (l >> 4) * 8;                              \
        aF[mf] = *(const short8*)&sA[buf][r * 128 +                           \
                                          (colu ^ ((r & 7) << 3))];           \
      }                                                                       \
      _Pragma("unroll") for (int mf = 0; mf < 2; ++mf)                        \
          _Pragma("unroll") for (int ci = 0; ci < 2; ++ci)                    \
              acc[mf][ci] = __builtin_amdgcn_mfma_f32_16x16x32_bf16(          \
                  aF[mf], Bf[kk * 2 + ci], acc[mf][ci], 0, 0, 0);             \
    }                                                                         \
    __builtin_amdgcn_s_setprio(0);                                            \
  } while (0)

#define LDS_BARRIER()                                                         \
  do {                                                                        \
    asm volatile("s_waitcnt lgkmcnt(0)" ::: "memory");                        \
    __builtin_amdgcn_sched_barrier(0);                                        \
    __builtin_amdgcn_s_barrier();                                             \
  } while (0)

template <int S>
__global__ __launch_bounds__(256, 4) void gcn_mm(
    const float* __restrict__ adj, const unsigned short* __restrict__ bfrag,
    unsigned short* __restrict__ parts, float* __restrict__ rowpart) {
  constexpr int KW = NN / S;       // K per slot
  constexpr int NS = KW / BK;      // steps (8 at S=8), always even
  __shared__ unsigned short sA[2][32 * 128];   // 16 KB

  const int t = threadIdx.x;
  const int l = t & 63;
  const int w = t >> 6;
  const int b = blockIdx.x;
  const int s = b & (S - 1);                  // K-slot == XCD (round-robin)
  const int row0 = (b / S) * 32;              // block's 32 rows
  const int kbase = s * KW;
  const int kt0 = s * (KW / 32);

  // A stage geometry: instr i, thread t -> row = i*8 + (t>>5), 512B/row chunks
  const int srow = t >> 5;                    // 0..7
  const int scol = (t & 31) * 4;              // f32 (and bf16) col within step
  const float* ap = adj + (size_t)(row0 + srow) * NN + kbase + scol;
  const unsigned short* bp = bfrag + (size_t)l * 8;

  f32x4 LrA[4], LrB[4];            // depth-2 A register stages
  ushort8v Bf[8];
  f32x4 acc[2][2] = {};
  float rs[4] = {};

  // prologue
  PREF(LrA, 0);
  STAGE(LrA, 0);                   // cold wait on step 0
  PREF(LrB, 1);                    // step 1 in flight across step 0's MFMA
  LDS_BARRIER();

  for (int st = 0; st < NS; st += 2) {
    // even: consume buf0
    LOAD_B(st);                                // B younger than A(st+1) queue-wise
    if (st + 2 < NS) PREF(LrA, st + 2);
    __builtin_amdgcn_sched_barrier(0);
    MFMA_STEP(0);                              // waits B only; A(st+2) survives
    STAGE(LrB, 1);                             // A(st+1): issued a full step ago
    LDS_BARRIER();
    // odd: consume buf1
    LOAD_B(st + 1);
    if (st + 3 < NS) PREF(LrB, st + 3);
    __builtin_amdgcn_sched_barrier(0);
    MFMA_STEP(1);
    if (st + 2 < NS) STAGE(LrA, 0);
    LDS_BARRIER();
  }

  // ---- rowsum: reduce over the 32 k-lanes sharing each row ----
  #pragma unroll
  for (int i = 0; i < 4; ++i) {
    rs[i] += __shfl_xor(rs[i], 1);
    rs[i] += __shfl_xor(rs[i], 2);
    rs[i] += __shfl_xor(rs[i], 4);
    rs[i] += __shfl_xor(rs[i], 8);
    rs[i] += __shfl_xor(rs[i], 16);
  }
  if ((l & 31) == 0) {
    #pragma unroll
    for (int i = 0; i < 4; ++i)
      rowpart[(size_t)s * NN + row0 + i * 8 + srow] = rs[i];
  }

  // ---- store bf16 partial tile: C/D col = l&15, row = (l>>4)*4 + j ----
  unsigned short* pp = parts + ((size_t)s * NN + row0) * FD + w * 32;
  #pragma unroll
  for (int mf = 0; mf < 2; ++mf)
    #pragma unroll
    for (int ci = 0; ci < 2; ++ci)
      #pragma unroll
      for (int j = 0; j < 4; ++j) {
        const int r = mf * 16 + ((l >> 4) << 2) + j;
        pp[(size_t)r * FD + ci * 16 + (l & 15)] = f2bf(acc[mf][ci][j]);
      }
}

// -------- Kernel 3: reduce S partials + epilogue ---------------------------
__global__ __launch_bounds__(256) void gcn_fin(
    const unsigned short* __restrict__ parts, const float* __restrict__ rowpart,
    const unsigned short* __restrict__ xk_rm, const float* __restrict__ beta,
    const float* __restrict__ bias, float* __restrict__ out, int S) {
  const int t = threadIdx.x;
  const int r = blockIdx.x * 16 + (t >> 4);
  const int c0 = (t & 15) * 8;

  float rsum = 0.f;
  for (int s = 0; s < S; ++s) rsum += rowpart[(size_t)s * NN + r];
  const float bt = beta[r];
  const float inv = 1.0f / (rsum + bt);

  float a[8] = {0.f, 0.f, 0.f, 0.f, 0.f, 0.f, 0.f, 0.f};
  for (int s = 0; s < S; ++s) {
    ushort8v pv = *(const ushort8v*)&parts[((size_t)s * NN + r) * FD + c0];
    #pragma unroll
    for (int q = 0; q < 8; ++q) a[q] += bf2f(pv[q]);
  }
  ushort8v xv = *(const ushort8v*)&xk_rm[(size_t)r * FD + c0];
  f32x4 o0, o1;
  #pragma unroll
  for (int q = 0; q < 4; ++q) {
    o0[q] = (a[q] + bt * bf2f(xv[q])) * inv + bias[c0 + q];
    o1[q] = (a[4 + q] + bt * bf2f(xv[4 + q])) * inv + bias[c0 + 4 + q];
  }
  *(f32x4*)&out[(size_t)r * FD + c0] = o0;
  *(f32x4*)&out[(size_t)r * FD + c0 + 4] = o1;
}

extern "C" void kernel_launch(void* const* d_in, const int* in_sizes, int n_in,
                              void* d_out, int out_size, void* d_ws, size_t ws_size,
                              hipStream_t stream) {
  const float* x    = (const float*)d_in[0];
  const float* adj  = (const float*)d_in[1];
  const float* kern = (const float*)d_in[2];
  const float* bias = (const float*)d_in[3];
  const float* beta = (const float*)d_in[4];
  float* out = (float*)d_out;

  char* ws = (char*)d_ws;
  unsigned short* bfrag = (unsigned short*)ws;                          // 2 MB
  unsigned short* xk_rm = (unsigned short*)(ws + (size_t)NN * FD * 2);  // 2 MB
  const size_t off_rowpart = (size_t)NN * FD * 4;
  float* rowpart = (float*)(ws + off_rowpart);                          // 256 KB
  const size_t off_parts = off_rowpart + (size_t)8 * NN * 4;
  unsigned short* parts = (unsigned short*)(ws + off_parts);            // 16 MB @ S=8

  int S = 8;
  while (S > 1 && off_parts + (size_t)S * NN * FD * 2 > ws_size) S >>= 1;

  hipLaunchKernelGGL(xk_kernel, dim3(NN / 16), dim3(256), 0, stream,
                     x, kern, bfrag, xk_rm);

  dim3 blk(256);
  switch (S) {
    case 8: hipLaunchKernelGGL(gcn_mm<8>, dim3(256 * 8), blk, 0, stream, adj, bfrag, parts, rowpart); break;
    case 4: hipLaunchKernelGGL(gcn_mm<4>, dim3(256 * 4), blk, 0, stream, adj, bfrag, parts, rowpart); break;
    case 2: hipLaunchKernelGGL(gcn_mm<2>, dim3(256 * 2), blk, 0, stream, adj, bfrag, parts, rowpart); break;
    default: hipLaunchKernelGGL(gcn_mm<1>, dim3(256), blk, 0, stream, adj, bfrag, parts, rowpart); break;
  }

  hipLaunchKernelGGL(gcn_fin, dim3(NN / 16), dim3(256), 0, stream,
                     parts, rowpart, xk_rm, beta, bias, out, S);
}